// Round 3
// baseline (4980.267 us; speedup 1.0000x reference)
//
#include <hip/hip_runtime.h>
#include <math.h>

#define BB 8
#define VV 2048
#define CC 32
#define TT 32
#define JJ 8192   // 4*V
#define NBLK 256

typedef unsigned short u16;
typedef unsigned int u32;
typedef short short8 __attribute__((ext_vector_type(8)));
typedef float f32x4 __attribute__((ext_vector_type(4)));

struct P {
  // inputs
  const float* Mvv; const int* ncol; const float* vh0; const float* ch0;
  const float* v0_wih; const float* v0_whh; const float* v0_bih; const float* v0_bhh;
  const float* v1_wih; const float* v1_whh; const float* v1_bih; const float* v1_bhh;
  const float* c_wih; const float* c_whh; const float* c_bih; const float* c_bhh;
  const float* cmsg_w; const float* cmsg_b; const float* vmsg_w; const float* vmsg_b;
  const float* vote_w; const float* vote_b;
  // workspace
  u16 *w0xP, *w0hP, *w1xP, *w1hP, *wvP, *wvoteP;   // packed B-frag weights
  u16 *h0A, *h1A, *mvA;                             // packed A-frag activations
  float *rs0, *bias0, *bias1;
  int *adj_cnt, *adj_cols;
  float *m0, *h1, *m1, *ch, *cm, *p1p, *scv, *vsum, *pacc;
  int* bar;
  float* out;
};

__device__ __forceinline__ u16 f2bf(float f) {
  u32 x = __float_as_uint(f);
  u32 r = (x + 0x7fffu + ((x >> 16) & 1u)) >> 16;
  return (u16)r;
}
__device__ __forceinline__ float sigm(float x) { return 1.f / (1.f + expf(-x)); }

// ============ setup kernels ============

// pack W[j][k] into MFMA-B tiles: tile (jt,kt): lane holds B[k=kt*32+(lane>>4)*8+i][n=jt*16+(lane&15)]
__global__ __launch_bounds__(256) void kPack(const float* __restrict__ src, int stride, int colOff,
                                             u16* __restrict__ dst) {
  int tile = blockIdx.x * 4 + (threadIdx.x >> 6);
  int lane = threadIdx.x & 63;
  int jt = tile >> 6, kt = tile & 63;
  int j = jt * 16 + (lane & 15);
  int k = colOff + kt * 32 + ((lane >> 4) << 3);
  const float* sp = src + (size_t)j * stride + k;
  float4 a = *(const float4*)sp;
  float4 b = *(const float4*)(sp + 4);
  uint4 pk;
  pk.x = (u32)f2bf(a.x) | ((u32)f2bf(a.y) << 16);
  pk.y = (u32)f2bf(a.z) | ((u32)f2bf(a.w) << 16);
  pk.z = (u32)f2bf(b.x) | ((u32)f2bf(b.y) << 16);
  pk.w = (u32)f2bf(b.z) | ((u32)f2bf(b.w) << 16);
  *(uint4*)(dst + (size_t)tile * 512 + lane * 8) = pk;
}

__global__ __launch_bounds__(256) void kRs0(P p) {
  int wid = threadIdx.x >> 6, lane = threadIdx.x & 63;
  int row = blockIdx.x * 4 + wid;
  const float* sp = p.v0_wih + (size_t)row * (2 * VV);
  float s = 0.f;
  for (int i = lane; i < VV; i += 64) s += sp[i];
#pragma unroll
  for (int d = 32; d > 0; d >>= 1) s += __shfl_down(s, d, 64);
  if (lane == 0) p.rs0[row] = s;
}

__global__ __launch_bounds__(256) void kAdj(P p) {
  int wid = threadIdx.x >> 6, lane = threadIdx.x & 63;
  int row = blockIdx.x * 4 + wid;   // b*2048+u
  const float* mp = p.Mvv + (size_t)row * VV;
  int* cols = p.adj_cols + (size_t)row * 64;
  int cnt = 0;
  for (int it = 0; it < 32; ++it) {
    float v = mp[it * 64 + lane];
    bool nz = v > 0.5f;
    unsigned long long mk = __ballot(nz);
    if (nz) {
      int pos = cnt + (int)__popcll(mk & ((1ull << lane) - 1ull));
      if (pos < 64) cols[pos] = it * 64 + lane;
    }
    cnt += (int)__popcll(mk);
  }
  if (lane == 0) p.adj_cnt[row] = cnt > 64 ? 64 : cnt;
}

__device__ __forceinline__ u32 apack_slot(const float* __restrict__ X, int slot) {
  int kt = slot >> 8;
  int r = slot & 255;
  int lane = r >> 2, w = r & 3;
  int b = lane & 15;
  if (b >= 8) return 0u;
  int k = kt * 32 + ((lane >> 4) << 3) + w * 2;
  return (u32)f2bf(X[b * VV + k]) | ((u32)f2bf(X[b * VV + k + 1]) << 16);
}

__device__ __forceinline__ void apack_write(u16* __restrict__ A, int b, int u, float v) {
  int kt = u >> 5, sub = (u >> 3) & 3, i = u & 7;
  A[((size_t)(kt * 64 + sub * 16 + b)) * 8 + i] = f2bf(v);
}

__global__ __launch_bounds__(256) void kInit(P p) {
  int i = blockIdx.x * 256 + threadIdx.x;  // 16384
  p.m0[i] = 0.f; p.m1[i] = 0.f;
  p.h1[i] = p.vh0[BB * VV + i];
  ((u32*)p.h0A)[i] = apack_slot(p.vh0, i);
  ((u32*)p.h1A)[i] = apack_slot(p.vh0 + BB * VV, i);
  ((u32*)p.mvA)[i] = 0u;
  if (i < JJ) { p.bias0[i] = p.v0_bih[i] + p.v0_bhh[i]; p.bias1[i] = p.v1_bih[i] + p.v1_bhh[i]; }
  if (i < BB * CC) { p.ch[i] = p.ch0[i]; p.cm[i] = 0.f; }
  if (i < 8) { p.pacc[i] = 0.f; p.vsum[i] = 0.f; p.scv[i] = 0.f; }
  if (i < 2) p.bar[i] = 0;
}

// ============ persistent main kernel ============

__device__ __forceinline__ void gridbar(int* bar) {
  __syncthreads();
  if (threadIdx.x == 0) {
    __threadfence();
    int g = __hip_atomic_load(&bar[1], __ATOMIC_RELAXED, __HIP_MEMORY_SCOPE_AGENT);
    int old = __hip_atomic_fetch_add(&bar[0], 1, __ATOMIC_ACQ_REL, __HIP_MEMORY_SCOPE_AGENT);
    if (old == NBLK - 1) {
      __hip_atomic_store(&bar[0], 0, __ATOMIC_RELAXED, __HIP_MEMORY_SCOPE_AGENT);
      __hip_atomic_fetch_add(&bar[1], 1, __ATOMIC_RELEASE, __HIP_MEMORY_SCOPE_AGENT);
    } else {
      while (__hip_atomic_load(&bar[1], __ATOMIC_RELAXED, __HIP_MEMORY_SCOPE_AGENT) == g)
        __builtin_amdgcn_s_sleep(2);
    }
    __threadfence();
  }
  __syncthreads();
}

__device__ __forceinline__ f32x4 mma_dual(const short8* __restrict__ a0, const short8* __restrict__ b0,
                                          const short8* __restrict__ a1, const short8* __restrict__ b1) {
  f32x4 c0 = {0.f, 0.f, 0.f, 0.f}, c1 = c0, c2 = c0, c3 = c0;
#pragma unroll 4
  for (int kt = 0; kt < 32; ++kt) {
    c0 = __builtin_amdgcn_mfma_f32_16x16x32_bf16(a0[kt * 64], b0[kt * 64], c0, 0, 0, 0);
    c1 = __builtin_amdgcn_mfma_f32_16x16x32_bf16(a0[(kt + 32) * 64], b0[(kt + 32) * 64], c1, 0, 0, 0);
    c2 = __builtin_amdgcn_mfma_f32_16x16x32_bf16(a1[kt * 64], b1[kt * 64], c2, 0, 0, 0);
    c3 = __builtin_amdgcn_mfma_f32_16x16x32_bf16(a1[(kt + 32) * 64], b1[(kt + 32) * 64], c3, 0, 0, 0);
  }
  return (c0 + c1) + (c2 + c3);
}

__device__ __forceinline__ f32x4 mma_one(const short8* __restrict__ a, const short8* __restrict__ b) {
  f32x4 c0 = {0.f, 0.f, 0.f, 0.f}, c1 = c0;
#pragma unroll 8
  for (int kt = 0; kt < 32; ++kt) {
    c0 = __builtin_amdgcn_mfma_f32_16x16x32_bf16(a[kt * 64], b[kt * 64], c0, 0, 0, 0);
    c1 = __builtin_amdgcn_mfma_f32_16x16x32_bf16(a[(kt + 32) * 64], b[(kt + 32) * 64], c1, 0, 0, 0);
  }
  return c0 + c1;
}

__global__ __launch_bounds__(256, 2) void kMain(P p) {
  const int bx = blockIdx.x, tid = threadIdx.x;
  const int wvid = tid >> 6, lane = tid & 63;
  const int n = lane & 15, rq = lane >> 4;
  __shared__ float smem[512];

  for (int t = 0; t < TT; ++t) {
    // ---- phase G: gather muled_v; color-msg scalar; zero vsum ----
    if (bx < 64) {
      int flat = (bx << 8) + tid, b = flat >> 11;
      int cnt = p.adj_cnt[flat];
      const int* cp = p.adj_cols + (size_t)flat * 64;
      const float* hb = p.h1 + (b << 11);
      float s = 0.f;
      for (int q = 0; q < cnt; ++q) s += hb[cp[q]];
      apack_write(p.mvA, b, flat & 2047, s);
    } else if (bx == NBLK - 1) {
      int b = tid >> 5, jc = tid & 31;
      float a = p.cmsg_b[jc];
      const float* chb = p.ch + b * CC;
#pragma unroll
      for (int k = 0; k < CC; ++k) a += chb[k] * p.cmsg_w[jc * CC + k];
      a = fmaxf(a, 0.f);
      smem[tid] = (jc < p.ncol[b]) ? a : 0.f;
      __syncthreads();
      if (tid < 8) {
        float s = 0.f;
        for (int j2 = 0; j2 < 32; ++j2) s += smem[tid * 32 + j2];
        p.scv[tid] = s; p.vsum[tid] = 0.f;
      }
    }
    gridbar(p.bar);
    // ---- phase A: gates0+LSTM0 (bx<128); part1 & vmsg (bx>=128) ----
    if (bx < 128) {
      int jt = wvid * 128 + bx;     // wave = gate
      f32x4 acc = mma_dual((const short8*)p.mvA + lane,
                           (const short8*)p.w0xP + (size_t)jt * 4096 + lane,
                           (const short8*)p.h0A + lane,
                           (const short8*)p.w0hP + (size_t)jt * 4096 + lane);
      if (rq < 2) {
#pragma unroll
        for (int r = 0; r < 4; ++r) smem[(wvid * 8 + rq * 4 + r) * 16 + n] = acc[r];
      }
      __syncthreads();
      if (tid < 128) {
        int b = tid >> 4, u16i = tid & 15, u = bx * 16 + u16i, flat = (b << 11) + u;
        float sv = p.scv[b];
        float g0 = smem[(0 * 8 + b) * 16 + u16i] + p.bias0[u]        + sv * p.rs0[u];
        float g1 = smem[(1 * 8 + b) * 16 + u16i] + p.bias0[2048 + u] + sv * p.rs0[2048 + u];
        float g2 = smem[(2 * 8 + b) * 16 + u16i] + p.bias0[4096 + u] + sv * p.rs0[4096 + u];
        float g3 = smem[(3 * 8 + b) * 16 + u16i] + p.bias0[6144 + u] + sv * p.rs0[6144 + u];
        float mn = sigm(g1) * p.m0[flat] + sigm(g0) * tanhf(g2);
        float hn = sigm(g3) * tanhf(mn);
        p.m0[flat] = mn;
        apack_write(p.h0A, b, u, hn);
      }
    } else {
      int jt = ((bx - 128) << 2) + wvid;   // 0..511 over part1 J
      f32x4 acc = mma_one((const short8*)p.h1A + lane,
                          (const short8*)p.w1hP + (size_t)jt * 4096 + lane);
      if (rq < 2) {
        float* op = p.p1p + (size_t)(rq * 4) * JJ + jt * 16 + n;
#pragma unroll
        for (int r = 0; r < 4; ++r) op[(size_t)r * JJ] = acc[r];
      }
      if (bx < 160) {
        int jv = ((bx - 128) << 2) + wvid; // 0..127 over vmsg J
        f32x4 av = mma_one((const short8*)p.h1A + lane,
                           (const short8*)p.wvP + (size_t)jv * 4096 + lane);
        float vals[4];
#pragma unroll
        for (int r = 0; r < 4; ++r)
          vals[r] = (rq < 2) ? fmaxf(av[r] + p.vmsg_b[jv * 16 + n], 0.f) : 0.f;
#pragma unroll
        for (int m = 1; m < 16; m <<= 1) {
#pragma unroll
          for (int r = 0; r < 4; ++r) vals[r] += __shfl_xor(vals[r], m, 64);
        }
        if (n == 0 && rq < 2) {
#pragma unroll
          for (int r = 0; r < 4; ++r) atomicAdd(&p.vsum[rq * 4 + r], vals[r]);
        }
      }
    }
    gridbar(p.bar);
    // ---- phase B: gates1+LSTM1 (bx<128); color LSTM (bx==128) ----
    if (bx < 128) {
      int jt = wvid * 128 + bx;
      f32x4 acc = mma_one((const short8*)p.h0A + lane,
                          (const short8*)p.w1xP + (size_t)jt * 4096 + lane);
      if (rq < 2) {
#pragma unroll
        for (int r = 0; r < 4; ++r) acc[r] += p.p1p[(size_t)(rq * 4 + r) * JJ + jt * 16 + n];
#pragma unroll
        for (int r = 0; r < 4; ++r) smem[(wvid * 8 + rq * 4 + r) * 16 + n] = acc[r];
      }
      __syncthreads();
      if (tid < 128) {
        int b = tid >> 4, u16i = tid & 15, u = bx * 16 + u16i, flat = (b << 11) + u;
        float g0 = smem[(0 * 8 + b) * 16 + u16i] + p.bias1[u];
        float g1 = smem[(1 * 8 + b) * 16 + u16i] + p.bias1[2048 + u];
        float g2 = smem[(2 * 8 + b) * 16 + u16i] + p.bias1[4096 + u];
        float g3 = smem[(3 * 8 + b) * 16 + u16i] + p.bias1[6144 + u];
        float mn = sigm(g1) * p.m1[flat] + sigm(g0) * tanhf(g2);
        float hn = sigm(g3) * tanhf(mn);
        p.m1[flat] = mn; p.h1[flat] = hn;
        apack_write(p.h1A, b, u, hn);
      }
    } else if (bx == 128) {
      int b = tid >> 5, jc = tid & 31;
      int nc = p.ncol[b];
      float vb = p.vsum[b];
      const float* chb = p.ch + b * CC;
      float g4[4];
#pragma unroll
      for (int g = 0; g < 4; ++g) {
        int j = g * CC + jc;
        float s = p.c_bih[j] + p.c_bhh[j];
        float ws = 0.f;
        for (int k = 0; k < nc; ++k) ws += p.c_wih[j * CC + k];
        s += vb * ws;
#pragma unroll
        for (int k = 0; k < CC; ++k) s += chb[k] * p.c_whh[j * CC + k];
        g4[g] = s;
      }
      __syncthreads();   // all reads of old ch done before any write
      float mn = sigm(g4[1]) * p.cm[tid] + sigm(g4[0]) * tanhf(g4[2]);
      float hn = sigm(g4[3]) * tanhf(mn);
      p.cm[tid] = mn; p.ch[tid] = hn;
    }
    gridbar(p.bar);
  }
  // ---- vote: MFMA over packed vote_w, sigmoid, mean ----
  if (bx < 32) {
    int jv = (bx << 2) + wvid;   // 0..127
    f32x4 av = mma_one((const short8*)p.h1A + lane,
                       (const short8*)p.wvoteP + (size_t)jv * 4096 + lane);
    float vals[4];
#pragma unroll
    for (int r = 0; r < 4; ++r)
      vals[r] = (rq < 2) ? sigm(av[r] + p.vote_b[jv * 16 + n]) : 0.f;
#pragma unroll
    for (int m = 1; m < 16; m <<= 1) {
#pragma unroll
      for (int r = 0; r < 4; ++r) vals[r] += __shfl_xor(vals[r], m, 64);
    }
    if (n == 0 && rq < 2) {
#pragma unroll
      for (int r = 0; r < 4; ++r) atomicAdd(&p.pacc[rq * 4 + r], vals[r]);
    }
  }
  gridbar(p.bar);
  if (bx == 0 && tid < 8) p.out[tid] = sigm(p.pacc[tid] * (1.f / (float)VV));
}

extern "C" void kernel_launch(void* const* d_in, const int* in_sizes, int n_in,
                              void* d_out, int out_size, void* d_ws, size_t ws_size,
                              hipStream_t stream) {
  P p;
  p.Mvv    = (const float*)d_in[0];
  p.ncol   = (const int*)d_in[1];
  p.vh0    = (const float*)d_in[2];
  p.ch0    = (const float*)d_in[3];
  p.v0_wih = (const float*)d_in[4];
  p.v0_whh = (const float*)d_in[5];
  p.v0_bih = (const float*)d_in[6];
  p.v0_bhh = (const float*)d_in[7];
  p.v1_wih = (const float*)d_in[8];
  p.v1_whh = (const float*)d_in[9];
  p.v1_bih = (const float*)d_in[10];
  p.v1_bhh = (const float*)d_in[11];
  p.c_wih  = (const float*)d_in[12];
  p.c_whh  = (const float*)d_in[13];
  p.c_bih  = (const float*)d_in[14];
  p.c_bhh  = (const float*)d_in[15];
  p.cmsg_w = (const float*)d_in[16];
  p.cmsg_b = (const float*)d_in[17];
  p.vmsg_w = (const float*)d_in[18];
  p.vmsg_b = (const float*)d_in[19];
  p.vote_w = (const float*)d_in[20];
  p.vote_b = (const float*)d_in[21];

  char* w = (char*)d_ws;
  size_t o = 0;
  auto alloc = [&](size_t bytes) -> void* {
    void* r = w + o;
    o = (o + bytes + 255) & ~(size_t)255;
    return r;
  };
  p.w0xP = (u16*)alloc((size_t)512 * 64 * 1024);
  p.w0hP = (u16*)alloc((size_t)512 * 64 * 1024);
  p.w1xP = (u16*)alloc((size_t)512 * 64 * 1024);
  p.w1hP = (u16*)alloc((size_t)512 * 64 * 1024);
  p.wvP    = (u16*)alloc((size_t)128 * 64 * 1024);
  p.wvoteP = (u16*)alloc((size_t)128 * 64 * 1024);
  p.h0A  = (u16*)alloc(64 * 1024);
  p.h1A  = (u16*)alloc(64 * 1024);
  p.mvA  = (u16*)alloc(64 * 1024);
  p.rs0   = (float*)alloc(JJ * 4);
  p.bias0 = (float*)alloc(JJ * 4);
  p.bias1 = (float*)alloc(JJ * 4);
  p.adj_cnt  = (int*)alloc((size_t)BB * VV * 4);
  p.adj_cols = (int*)alloc((size_t)BB * VV * 64 * 4);
  p.m0 = (float*)alloc((size_t)BB * VV * 4);
  p.h1 = (float*)alloc((size_t)BB * VV * 4);
  p.m1 = (float*)alloc((size_t)BB * VV * 4);
  p.ch = (float*)alloc(BB * CC * 4);
  p.cm = (float*)alloc(BB * CC * 4);
  p.p1p = (float*)alloc((size_t)BB * JJ * 4);
  p.scv  = (float*)alloc(256);
  p.vsum = (float*)alloc(256);
  p.pacc = (float*)alloc(256);
  p.bar  = (int*)alloc(256);
  p.out = (float*)d_out;

  kPack<<<8192, 256, 0, stream>>>(p.v0_wih, 2 * VV, VV, p.w0xP);
  kPack<<<8192, 256, 0, stream>>>(p.v0_whh, VV, 0, p.w0hP);
  kPack<<<8192, 256, 0, stream>>>(p.v1_wih, VV, 0, p.w1xP);
  kPack<<<8192, 256, 0, stream>>>(p.v1_whh, VV, 0, p.w1hP);
  kPack<<<2048, 256, 0, stream>>>(p.vmsg_w, VV, 0, p.wvP);
  kPack<<<2048, 256, 0, stream>>>(p.vote_w, VV, 0, p.wvoteP);
  kRs0<<<2048, 256, 0, stream>>>(p);
  kAdj<<<4096, 256, 0, stream>>>(p);
  kInit<<<64, 256, 0, stream>>>(p);

  kMain<<<NBLK, 256, 0, stream>>>(p);
}

// Round 4
// 2877.038 us; speedup vs baseline: 1.7310x; 1.7310x over previous
//
#include <hip/hip_runtime.h>
#include <math.h>

#define BB 8
#define VV 2048
#define CC 32
#define TT 32
#define JJ 8192   // 4*V
#define NBLK 256

typedef unsigned short u16;
typedef unsigned int u32;
typedef unsigned long long u64;
typedef short short8 __attribute__((ext_vector_type(8)));
typedef float f32x4 __attribute__((ext_vector_type(4)));

struct P {
  // inputs
  const float* Mvv; const int* ncol; const float* vh0; const float* ch0;
  const float* v0_wih; const float* v0_whh; const float* v0_bih; const float* v0_bhh;
  const float* v1_wih; const float* v1_whh; const float* v1_bih; const float* v1_bhh;
  const float* c_wih; const float* c_whh; const float* c_bih; const float* c_bhh;
  const float* cmsg_w; const float* cmsg_b; const float* vmsg_w; const float* vmsg_b;
  const float* vote_w; const float* vote_b;
  // workspace
  u16 *w0xP, *w0hP, *w1xP, *w1hP, *wvP, *wvoteP;   // packed B-frag weights (cached reads)
  u16 *h0A, *h1A, *mvA;                             // packed A-frag activations (coherent via atomics)
  float *rs0, *bias0, *bias1;
  int *adj_cnt, *adj_cols;
  float *m0, *h1, *m1, *ch, *cm, *p1p, *scv, *vsum, *pacc;
  int* bar;
  float* out;
};

__device__ __forceinline__ u16 f2bf(float f) {
  u32 x = __float_as_uint(f);
  u32 r = (x + 0x7fffu + ((x >> 16) & 1u)) >> 16;
  return (u16)r;
}
__device__ __forceinline__ float sigm(float x) { return 1.f / (1.f + expf(-x)); }

// ---- agent-scope coherent (L2-bypassing) accessors ----
__device__ __forceinline__ float aldf(const float* p) {
  u32 x = __hip_atomic_load((const u32*)p, __ATOMIC_RELAXED, __HIP_MEMORY_SCOPE_AGENT);
  return __uint_as_float(x);
}
__device__ __forceinline__ void astf(float* p, float v) {
  __hip_atomic_store((u32*)p, __float_as_uint(v), __ATOMIC_RELAXED, __HIP_MEMORY_SCOPE_AGENT);
}
__device__ __forceinline__ u32 aldu(const u32* p) {
  return __hip_atomic_load(p, __ATOMIC_RELAXED, __HIP_MEMORY_SCOPE_AGENT);
}
__device__ __forceinline__ void astu(u32* p, u32 v) {
  __hip_atomic_store(p, v, __ATOMIC_RELAXED, __HIP_MEMORY_SCOPE_AGENT);
}
__device__ __forceinline__ void ast64(u64* p, u64 v) {
  __hip_atomic_store(p, v, __ATOMIC_RELAXED, __HIP_MEMORY_SCOPE_AGENT);
}
__device__ __forceinline__ short8 aload(const short8* p) {
  const u64* q = (const u64*)p;
  union { u64 q[2]; short8 v; } u;
  u.q[0] = __hip_atomic_load(q, __ATOMIC_RELAXED, __HIP_MEMORY_SCOPE_AGENT);
  u.q[1] = __hip_atomic_load(q + 1, __ATOMIC_RELAXED, __HIP_MEMORY_SCOPE_AGENT);
  return u.v;
}

// ============ setup kernels ============

__global__ __launch_bounds__(256) void kPack(const float* __restrict__ src, int stride, int colOff,
                                             u16* __restrict__ dst) {
  int tile = blockIdx.x * 4 + (threadIdx.x >> 6);
  int lane = threadIdx.x & 63;
  int jt = tile >> 6, kt = tile & 63;
  int j = jt * 16 + (lane & 15);
  int k = colOff + kt * 32 + ((lane >> 4) << 3);
  const float* sp = src + (size_t)j * stride + k;
  float4 a = *(const float4*)sp;
  float4 b = *(const float4*)(sp + 4);
  uint4 pk;
  pk.x = (u32)f2bf(a.x) | ((u32)f2bf(a.y) << 16);
  pk.y = (u32)f2bf(a.z) | ((u32)f2bf(a.w) << 16);
  pk.z = (u32)f2bf(b.x) | ((u32)f2bf(b.y) << 16);
  pk.w = (u32)f2bf(b.z) | ((u32)f2bf(b.w) << 16);
  *(uint4*)(dst + (size_t)tile * 512 + lane * 8) = pk;
}

__global__ __launch_bounds__(256) void kRs0(P p) {
  int wid = threadIdx.x >> 6, lane = threadIdx.x & 63;
  int row = blockIdx.x * 4 + wid;
  const float* sp = p.v0_wih + (size_t)row * (2 * VV);
  float s = 0.f;
  for (int i = lane; i < VV; i += 64) s += sp[i];
#pragma unroll
  for (int d = 32; d > 0; d >>= 1) s += __shfl_down(s, d, 64);
  if (lane == 0) p.rs0[row] = s;
}

__global__ __launch_bounds__(256) void kAdj(P p) {
  int wid = threadIdx.x >> 6, lane = threadIdx.x & 63;
  int row = blockIdx.x * 4 + wid;   // b*2048+u
  const float* mp = p.Mvv + (size_t)row * VV;
  int* cols = p.adj_cols + (size_t)row * 64;
  int cnt = 0;
  for (int it = 0; it < 32; ++it) {
    float v = mp[it * 64 + lane];
    bool nz = v > 0.5f;
    unsigned long long mk = __ballot(nz);
    if (nz) {
      int pos = cnt + (int)__popcll(mk & ((1ull << lane) - 1ull));
      if (pos < 64) cols[pos] = it * 64 + lane;
    }
    cnt += (int)__popcll(mk);
  }
  if (lane == 0) p.adj_cnt[row] = cnt > 64 ? 64 : cnt;
}

__device__ __forceinline__ u32 apack_slot(const float* __restrict__ X, int slot) {
  int kt = slot >> 8;
  int r = slot & 255;
  int lane = r >> 2, w = r & 3;
  int b = lane & 15;
  if (b >= 8) return 0u;
  int k = kt * 32 + ((lane >> 4) << 3) + w * 2;
  return (u32)f2bf(X[b * VV + k]) | ((u32)f2bf(X[b * VV + k + 1]) << 16);
}

__global__ __launch_bounds__(256) void kInit(P p) {
  int i = blockIdx.x * 256 + threadIdx.x;  // 16384
  p.m0[i] = 0.f; p.m1[i] = 0.f;
  p.h1[i] = p.vh0[BB * VV + i];
  ((u32*)p.h0A)[i] = apack_slot(p.vh0, i);        // buffer 0
  ((u32*)p.h0A)[16384 + i] = 0u;                  // buffer 1 (padding rows stay 0)
  ((u32*)p.h1A)[i] = apack_slot(p.vh0 + BB * VV, i);
  ((u32*)p.mvA)[i] = 0u;
  if (i < JJ) { p.bias0[i] = p.v0_bih[i] + p.v0_bhh[i]; p.bias1[i] = p.v1_bih[i] + p.v1_bhh[i]; }
  if (i < BB * CC) { p.ch[i] = p.ch0[i]; p.cm[i] = 0.f; }
  if (i < 8) { p.pacc[i] = 0.f; p.vsum[i] = 0.f; p.scv[i] = 0.f; }
  if (i < 2048) p.bar[i] = 0;
}

// ============ persistent main kernel ============

// tree barrier: 16 groups x 16 blocks; monotonic generation targets.
// bar[0]=root ctr, bar[16]=root gen, bar[64+g*64]=group ctr, bar[64+g*64+16]=group gen
__device__ __forceinline__ void gridbar(int* bar, int tgt) {
  __syncthreads();   // compiler emits full vmcnt drain before s_barrier -> stores visible at L3
  if (threadIdx.x == 0) {
    int g = blockIdx.x & 15;
    int* gctr = bar + 64 + g * 64;
    int* ggen = gctr + 16;
    int old = __hip_atomic_fetch_add(gctr, 1, __ATOMIC_RELEASE, __HIP_MEMORY_SCOPE_AGENT);
    if ((old & 15) == 15) {   // group leader
      int ro = __hip_atomic_fetch_add(bar, 1, __ATOMIC_ACQ_REL, __HIP_MEMORY_SCOPE_AGENT);
      if ((ro & 15) == 15) {  // last group
        __hip_atomic_store(bar + 16, tgt, __ATOMIC_RELAXED, __HIP_MEMORY_SCOPE_AGENT);
      } else {
        while (__hip_atomic_load(bar + 16, __ATOMIC_RELAXED, __HIP_MEMORY_SCOPE_AGENT) < tgt)
          __builtin_amdgcn_s_sleep(1);
      }
      __hip_atomic_store(ggen, tgt, __ATOMIC_RELAXED, __HIP_MEMORY_SCOPE_AGENT);
    } else {
      while (__hip_atomic_load(ggen, __ATOMIC_RELAXED, __HIP_MEMORY_SCOPE_AGENT) < tgt)
        __builtin_amdgcn_s_sleep(1);
    }
  }
  __syncthreads();
}

// 32 K-tiles of one (A,B) pair; A via coherent loads, B via cached loads
__device__ __forceinline__ f32x4 mma32(const short8* __restrict__ a, const short8* __restrict__ b) {
  f32x4 c0 = {0.f, 0.f, 0.f, 0.f}, c1 = c0;
#pragma unroll 8
  for (int m = 0; m < 32; m += 2) {
    c0 = __builtin_amdgcn_mfma_f32_16x16x32_bf16(aload(a + (size_t)m * 64), b[(size_t)m * 64], c0, 0, 0, 0);
    c1 = __builtin_amdgcn_mfma_f32_16x16x32_bf16(aload(a + (size_t)(m + 1) * 64), b[(size_t)(m + 1) * 64], c1, 0, 0, 0);
  }
  return c0 + c1;
}

__global__ __launch_bounds__(512, 2) void kMain(P p) {
  const int bx = blockIdx.x, tid = threadIdx.x;
  const int w = tid >> 6, lane = tid & 63;
  const int n = lane & 15, rq = lane >> 4;
  __shared__ float sm[8][8][16];
  __shared__ float sm2[8][8][16];
  __shared__ float red[512];
  int tgt = 0;

  for (int t = 0; t < TT; ++t) {
    u16* h0r = p.h0A + (size_t)(t & 1) * 32768;        // read buffer (u16 units)
    u16* h0w = p.h0A + (size_t)((t + 1) & 1) * 32768;  // write buffer
    // ---------- phase G: gather muled_v; color message ----------
    if (bx < 32) {
      if (tid < 256) {
        int base = (bx << 9) + (tid << 1);   // 2 u per thread
        int b = base >> 11;
        const float* hb = p.h1 + (b << 11);
        u32 pk = 0;
#pragma unroll
        for (int e = 0; e < 2; ++e) {
          int flat = base + e;
          int cnt = p.adj_cnt[flat];
          const int* cp = p.adj_cols + (size_t)flat * 64;
          float s = 0.f;
          for (int q = 0; q < cnt; ++q) s += aldf(hb + cp[q]);
          pk |= (u32)f2bf(s) << (e * 16);
        }
        int u0 = base & 2047;
        int kt = u0 >> 5, sub = (u0 >> 3) & 3, ii = u0 & 7;
        astu((u32*)(p.mvA + ((size_t)(kt * 64 + sub * 16 + b)) * 8 + ii), pk);
      }
    } else if (bx == 255) {
      if (tid < 256) {
        int b = tid >> 5, jc = tid & 31;
        float a = p.cmsg_b[jc];
#pragma unroll
        for (int k = 0; k < CC; ++k) a += aldf(p.ch + b * CC + k) * p.cmsg_w[jc * CC + k];
        a = fmaxf(a, 0.f);
        red[tid] = (jc < p.ncol[b]) ? a : 0.f;
      }
      __syncthreads();
      if (tid < 8) {
        float s = 0.f;
        for (int jc = 0; jc < 32; ++jc) s += red[tid * 32 + jc];
        astf(p.scv + tid, s);
        astf(p.vsum + tid, 0.f);
      }
    }
    gridbar(p.bar, ++tgt);
    // ---------- phase A: gates0+LSTM0 (bx<128); part1+vmsg (bx>=128) ----------
    if (bx < 128) {
      int g = w >> 1, h = w & 1;
      size_t jt = (size_t)g * 128 + bx;
      int k0 = h * 32;
      f32x4 acc = mma32((const short8*)p.mvA + (size_t)k0 * 64 + lane,
                        (const short8*)p.w0xP + jt * 4096 + (size_t)k0 * 64 + lane);
      f32x4 acc2 = mma32((const short8*)h0r + (size_t)k0 * 64 + lane,
                         (const short8*)p.w0hP + jt * 4096 + (size_t)k0 * 64 + lane);
      acc += acc2;
      if (rq < 2) {
#pragma unroll
        for (int r = 0; r < 4; ++r) sm[w][rq * 4 + r][n] = acc[r];
      }
      __syncthreads();
      if (tid < 64) {
        int b = tid >> 3, up = (tid & 7) << 1;
        float sv = aldf(p.scv + b);
        u32 pk = 0;
#pragma unroll
        for (int e = 0; e < 2; ++e) {
          int ui = up + e, u = (bx << 4) + ui, flat = (b << 11) + u;
          float g0 = sm[0][b][ui] + sm[1][b][ui] + p.bias0[u]        + sv * p.rs0[u];
          float g1 = sm[2][b][ui] + sm[3][b][ui] + p.bias0[2048 + u] + sv * p.rs0[2048 + u];
          float g2 = sm[4][b][ui] + sm[5][b][ui] + p.bias0[4096 + u] + sv * p.rs0[4096 + u];
          float g3 = sm[6][b][ui] + sm[7][b][ui] + p.bias0[6144 + u] + sv * p.rs0[6144 + u];
          float mn = sigm(g1) * p.m0[flat] + sigm(g0) * tanhf(g2);
          float hn = sigm(g3) * tanhf(mn);
          p.m0[flat] = mn;
          pk |= (u32)f2bf(hn) << (e * 16);
        }
        int u0 = (bx << 4) + up;
        int kt = u0 >> 5, sub = (u0 >> 3) & 3, ii = u0 & 7;
        astu((u32*)(h0w + ((size_t)(kt * 64 + sub * 16 + b)) * 8 + ii), pk);
      }
    } else {
      // job1: part1  jt = (bx-128)*4 + (w>>1), half = w&1
      {
        size_t jt = (size_t)(bx - 128) * 4 + (w >> 1);
        int k0 = (w & 1) * 32;
        f32x4 acc = mma32((const short8*)p.h1A + (size_t)k0 * 64 + lane,
                          (const short8*)p.w1hP + jt * 4096 + (size_t)k0 * 64 + lane);
        if (rq < 2) {
#pragma unroll
          for (int r = 0; r < 4; ++r) sm[w][rq * 4 + r][n] = acc[r];
        }
      }
      // job2: vmsg for blocks 128..159
      if (bx < 160) {
        size_t jv = (size_t)(bx - 128) * 4 + (w >> 1);
        int k0 = (w & 1) * 32;
        f32x4 acc = mma32((const short8*)p.h1A + (size_t)k0 * 64 + lane,
                          (const short8*)p.wvP + jv * 4096 + (size_t)k0 * 64 + lane);
        if (rq < 2) {
#pragma unroll
          for (int r = 0; r < 4; ++r) sm2[w][rq * 4 + r][n] = acc[r];
        }
      }
      __syncthreads();
      {
        int jl = tid >> 7, r = (tid >> 4) & 7, nn = tid & 15;
        float v = sm[jl * 2][r][nn] + sm[jl * 2 + 1][r][nn];
        int jt = (bx - 128) * 4 + jl;
        astu((u32*)(p.p1p + (size_t)r * JJ + jt * 16 + nn), __float_as_uint(v));
      }
      if (bx < 160) {
        int jl = tid >> 7, r = (tid >> 4) & 7, nn = tid & 15;
        int jv = (bx - 128) * 4 + jl;
        float v = sm2[jl * 2][r][nn] + sm2[jl * 2 + 1][r][nn];
        red[tid] = fmaxf(v + p.vmsg_b[jv * 16 + nn], 0.f);
        __syncthreads();
        if (tid < 8) {
          float s = 0.f;
          for (int jl2 = 0; jl2 < 4; ++jl2)
            for (int nn2 = 0; nn2 < 16; ++nn2) s += red[jl2 * 128 + tid * 16 + nn2];
          atomicAdd(p.vsum + tid, s);
        }
      }
    }
    gridbar(p.bar, ++tgt);
    // ---------- phase B: gates1+LSTM1 (bx<128); color LSTM (bx==128) ----------
    if (bx < 128) {
      int g = w >> 1, h = w & 1;
      size_t jt = (size_t)g * 128 + bx;
      int k0 = h * 32;
      f32x4 acc = mma32((const short8*)h0w + (size_t)k0 * 64 + lane,
                        (const short8*)p.w1xP + jt * 4096 + (size_t)k0 * 64 + lane);
      if (rq < 2) {
#pragma unroll
        for (int r = 0; r < 4; ++r) sm[w][rq * 4 + r][n] = acc[r];
      }
      __syncthreads();
      if (tid < 64) {
        int b = tid >> 3, up = (tid & 7) << 1;
        u32 pk = 0;
        float hf[2];
#pragma unroll
        for (int e = 0; e < 2; ++e) {
          int ui = up + e, u = (bx << 4) + ui, flat = (b << 11) + u;
          const float* pb = p.p1p + (size_t)b * JJ;
          float g0 = sm[0][b][ui] + sm[1][b][ui] + p.bias1[u]        + aldf(pb + u);
          float g1 = sm[2][b][ui] + sm[3][b][ui] + p.bias1[2048 + u] + aldf(pb + 2048 + u);
          float g2 = sm[4][b][ui] + sm[5][b][ui] + p.bias1[4096 + u] + aldf(pb + 4096 + u);
          float g3 = sm[6][b][ui] + sm[7][b][ui] + p.bias1[6144 + u] + aldf(pb + 6144 + u);
          float mn = sigm(g1) * p.m1[flat] + sigm(g0) * tanhf(g2);
          float hn = sigm(g3) * tanhf(mn);
          p.m1[flat] = mn;
          hf[e] = hn;
          pk |= (u32)f2bf(hn) << (e * 16);
        }
        int u0 = (bx << 4) + up;
        u64 hq = ((u64)__float_as_uint(hf[1]) << 32) | (u64)__float_as_uint(hf[0]);
        ast64((u64*)(p.h1 + (b << 11) + u0), hq);
        int kt = u0 >> 5, sub = (u0 >> 3) & 3, ii = u0 & 7;
        astu((u32*)(p.h1A + ((size_t)(kt * 64 + sub * 16 + b)) * 8 + ii), pk);
      }
    } else if (bx == 128) {
      float g4[4] = {0.f, 0.f, 0.f, 0.f};
      int b = tid >> 5, jc = tid & 31;
      if (tid < 256) {
        int nc = p.ncol[b];
        float vb = aldf(p.vsum + b);
#pragma unroll
        for (int g = 0; g < 4; ++g) {
          int j = g * CC + jc;
          float s = p.c_bih[j] + p.c_bhh[j];
          float ws = 0.f;
          for (int k = 0; k < nc; ++k) ws += p.c_wih[j * CC + k];
          g4[g] = s + vb * ws;
        }
        for (int k = 0; k < CC; ++k) {
          float c = aldf(p.ch + b * CC + k);
#pragma unroll
          for (int g = 0; g < 4; ++g) g4[g] += c * p.c_whh[(g * CC + jc) * CC + k];
        }
      }
      __syncthreads();
      if (tid < 256) {
        float mn = sigm(g4[1]) * p.cm[tid] + sigm(g4[0]) * tanhf(g4[2]);
        float hn = sigm(g4[3]) * tanhf(mn);
        p.cm[tid] = mn;
        astf(p.ch + tid, hn);
      }
    }
    gridbar(p.bar, ++tgt);
  }
  // ---------- vote ----------
  if (bx < 32) {
    size_t jv = (size_t)bx * 4 + (w >> 1);
    int k0 = (w & 1) * 32;
    f32x4 acc = mma32((const short8*)p.h1A + (size_t)k0 * 64 + lane,
                      (const short8*)p.wvoteP + jv * 4096 + (size_t)k0 * 64 + lane);
    if (rq < 2) {
#pragma unroll
      for (int r = 0; r < 4; ++r) sm[w][rq * 4 + r][n] = acc[r];
    }
    __syncthreads();
    {
      int jl = tid >> 7, r = (tid >> 4) & 7, nn = tid & 15;
      float v = sm[jl * 2][r][nn] + sm[jl * 2 + 1][r][nn];
      red[tid] = sigm(v + p.vote_b[(bx * 4 + jl) * 16 + nn]);
    }
    __syncthreads();
    if (tid < 8) {
      float s = 0.f;
      for (int jl2 = 0; jl2 < 4; ++jl2)
        for (int nn2 = 0; nn2 < 16; ++nn2) s += red[jl2 * 128 + tid * 16 + nn2];
      atomicAdd(p.pacc + tid, s);
    }
  }
  gridbar(p.bar, ++tgt);
  if (bx == 0 && tid < 8) p.out[tid] = sigm(aldf(p.pacc + tid) * (1.f / (float)VV));
}

extern "C" void kernel_launch(void* const* d_in, const int* in_sizes, int n_in,
                              void* d_out, int out_size, void* d_ws, size_t ws_size,
                              hipStream_t stream) {
  P p;
  p.Mvv    = (const float*)d_in[0];
  p.ncol   = (const int*)d_in[1];
  p.vh0    = (const float*)d_in[2];
  p.ch0    = (const float*)d_in[3];
  p.v0_wih = (const float*)d_in[4];
  p.v0_whh = (const float*)d_in[5];
  p.v0_bih = (const float*)d_in[6];
  p.v0_bhh = (const float*)d_in[7];
  p.v1_wih = (const float*)d_in[8];
  p.v1_whh = (const float*)d_in[9];
  p.v1_bih = (const float*)d_in[10];
  p.v1_bhh = (const float*)d_in[11];
  p.c_wih  = (const float*)d_in[12];
  p.c_whh  = (const float*)d_in[13];
  p.c_bih  = (const float*)d_in[14];
  p.c_bhh  = (const float*)d_in[15];
  p.cmsg_w = (const float*)d_in[16];
  p.cmsg_b = (const float*)d_in[17];
  p.vmsg_w = (const float*)d_in[18];
  p.vmsg_b = (const float*)d_in[19];
  p.vote_w = (const float*)d_in[20];
  p.vote_b = (const float*)d_in[21];

  char* w = (char*)d_ws;
  size_t o = 0;
  auto alloc = [&](size_t bytes) -> void* {
    void* r = w + o;
    o = (o + bytes + 255) & ~(size_t)255;
    return r;
  };
  p.w0xP = (u16*)alloc((size_t)512 * 64 * 1024);
  p.w0hP = (u16*)alloc((size_t)512 * 64 * 1024);
  p.w1xP = (u16*)alloc((size_t)512 * 64 * 1024);
  p.w1hP = (u16*)alloc((size_t)512 * 64 * 1024);
  p.wvP    = (u16*)alloc((size_t)128 * 64 * 1024);
  p.wvoteP = (u16*)alloc((size_t)128 * 64 * 1024);
  p.h0A  = (u16*)alloc(2 * 64 * 1024);
  p.h1A  = (u16*)alloc(64 * 1024);
  p.mvA  = (u16*)alloc(64 * 1024);
  p.rs0   = (float*)alloc(JJ * 4);
  p.bias0 = (float*)alloc(JJ * 4);
  p.bias1 = (float*)alloc(JJ * 4);
  p.adj_cnt  = (int*)alloc((size_t)BB * VV * 4);
  p.adj_cols = (int*)alloc((size_t)BB * VV * 64 * 4);
  p.m0 = (float*)alloc((size_t)BB * VV * 4);
  p.h1 = (float*)alloc((size_t)BB * VV * 4);
  p.m1 = (float*)alloc((size_t)BB * VV * 4);
  p.ch = (float*)alloc(BB * CC * 4);
  p.cm = (float*)alloc(BB * CC * 4);
  p.p1p = (float*)alloc((size_t)BB * JJ * 4);
  p.scv  = (float*)alloc(256);
  p.vsum = (float*)alloc(256);
  p.pacc = (float*)alloc(256);
  p.bar  = (int*)alloc(8192);
  p.out = (float*)d_out;

  kPack<<<8192, 256, 0, stream>>>(p.v0_wih, 2 * VV, VV, p.w0xP);
  kPack<<<8192, 256, 0, stream>>>(p.v0_whh, VV, 0, p.w0hP);
  kPack<<<8192, 256, 0, stream>>>(p.v1_wih, VV, 0, p.w1xP);
  kPack<<<8192, 256, 0, stream>>>(p.v1_whh, VV, 0, p.w1hP);
  kPack<<<2048, 256, 0, stream>>>(p.vmsg_w, VV, 0, p.wvP);
  kPack<<<2048, 256, 0, stream>>>(p.vote_w, VV, 0, p.wvoteP);
  kRs0<<<2048, 256, 0, stream>>>(p);
  kAdj<<<4096, 256, 0, stream>>>(p);
  kInit<<<64, 256, 0, stream>>>(p);

  kMain<<<NBLK, 512, 0, stream>>>(p);
}